// Round 9
// baseline (390.238 us; speedup 1.0000x reference)
//
#include <hip/hip_runtime.h>
#include <stdint.h>
#include <stddef.h>

typedef __bf16 bf16x8 __attribute__((ext_vector_type(8)));
typedef float floatx4 __attribute__((ext_vector_type(4)));
typedef unsigned short u16;

__device__ __forceinline__ float bf2f(u16 h) {
    unsigned u = ((unsigned)h) << 16;
    return __builtin_bit_cast(float, u);
}
__device__ __forceinline__ u16 f2bf(float f) {
    unsigned u = __builtin_bit_cast(unsigned, f);
    u += 0x7fffu + ((u >> 16) & 1u);   // round-to-nearest-even
    return (u16)(u >> 16);
}

// async global->LDS, 16B per lane; lds dest is wave-uniform base (+lane*16 implicit)
__device__ __forceinline__ void gload16(const void* g, void* l) {
    __builtin_amdgcn_global_load_lds(
        (const __attribute__((address_space(1))) uint32_t*)g,
        (__attribute__((address_space(3))) uint32_t*)l, 16, 0, 0);
}

// counted vmcnt waits (literal strings required)
__device__ __forceinline__ void wait_vm6() { asm volatile("s_waitcnt vmcnt(6)" ::: "memory"); }
__device__ __forceinline__ void wait_vm3() { asm volatile("s_waitcnt vmcnt(3)" ::: "memory"); }
__device__ __forceinline__ void wait_vm0() { asm volatile("s_waitcnt vmcnt(0)" ::: "memory"); }

// ---------------- R9 mega-preprocessing: x-cast + 4 weight transposes, one dispatch ----------------
// blocks [0,4096): conv_x; [4096,10240): convT wq; [10240,11520): convT wkva (pads N to 640);
// [11520,13568): convT wkvb; [13568,17664): convT wo. All independent; branch is block-uniform.
__global__ __launch_bounds__(256) void k_preproc(const float* __restrict__ x_raw, u16* __restrict__ x_bf,
                                                 const float* __restrict__ wq, const float* __restrict__ wkva,
                                                 const float* __restrict__ wkvb, const float* __restrict__ wo,
                                                 u16* __restrict__ g12bt, u16* __restrict__ wkvb_t,
                                                 u16* __restrict__ wo_t) {
    __shared__ u16 t[32][33];
    int bid = blockIdx.x, tid = threadIdx.x;
    if (bid < 4096) {
        int i = bid * 256 + tid;          // < 1048576 exact
        const float* f = x_raw + (size_t)i * 8;
        unsigned o[4];
        for (int q = 0; q < 4; q++) {
            u16 lo = f2bf(f[2 * q]), hi = f2bf(f[2 * q + 1]);
            o[q] = (unsigned)lo | ((unsigned)hi << 16);
        }
        uint4 p = {o[0], o[1], o[2], o[3]};
        *(uint4*)&x_bf[(size_t)i * 8] = p;
        return;
    }
    const float* in; u16* out; int K, N, bx, by;
    if (bid < 10240)      { int i = bid - 4096;  in = wq;   out = g12bt;                       K = 2048; N = 3072; bx = i & 63; by = i >> 6; }
    else if (bid < 11520) { int i = bid - 10240; in = wkva; out = g12bt + (size_t)3072 * 2048; K = 2048; N = 576;  bx = i & 63; by = i >> 6; }
    else if (bid < 13568) { int i = bid - 11520; in = wkvb; out = wkvb_t;                      K = 512;  N = 4096; bx = i & 15; by = i >> 4; }
    else                  { int i = bid - 13568; in = wo;   out = wo_t;                        K = 2048; N = 2048; bx = i & 63; by = i >> 6; }
    int k0 = bx * 32, n0 = by * 32;
    int c = tid & 31, r8 = tid >> 5;
    for (int j = 0; j < 4; j++) {
        int row = r8 + j * 8;
        int n = n0 + c;
        t[row][c] = (n < N) ? f2bf(in[(size_t)(k0 + row) * N + n]) : (u16)0;
    }
    __syncthreads();
    for (int j = 0; j < 4; j++) {
        int row = r8 + j * 8;
        out[(size_t)(n0 + row) * K + k0 + c] = t[c][row];
    }
}

// ---------------- 256x128 ring-pipelined GEMM + fragment double-buffer (R8, unchanged core) ----
// 4-slot LDS ring of BK=32 subtiles, prefetch 3 ahead, counted vmcnt (never 0 in steady
// loop), one barrier per subtile; fragments double-buffered in NAMED register sets.
// st_16x32 swizzle in 1KiB subtiles; gload_lds writes linear, global source inverse-swizzled.
// MODE: 0 = u16 out; 1 = f32 out;
//       2 = split store: col<3072 -> C0 u16 ldc 3072; 3072<=col<3648 -> C1 u16 ldc 576.
//       3 = GEMM3 fusion (R9: kv PACKED ldc 2048): (col%256)<128 -> C0[row*2048 + (col>>8)*128 + cm];
//           else v-part -> vt (C1) TRANSPOSED: vt[((b*16+h)*128+vd)*2048 + s], uint2 packed.
template <int NWC, int MODE>
__global__ __launch_bounds__(512, 2) void k_gemm256(const u16* __restrict__ A,
                                                    const u16* __restrict__ BT,
                                                    void* __restrict__ C0,
                                                    void* __restrict__ C1,
                                                    int K, int ldc) {
    constexpr int MFR = 16 / (8 / NWC);     // NWC=2 -> 4
    constexpr int ACH = 2;
    constexpr int BCH = NWC / 2;
    constexpr int SLOT = 8192 + NWC * 2048;
    __shared__ __align__(16) u16 RING[4][SLOT];
    int tid = threadIdx.x;
    int w = tid >> 6, lane = tid & 63;
    int l15 = lane & 15, quad = lane >> 4;
    int wr = w / NWC, wc = w % NWC;

    // XCD-aware swizzle (bijective: nwg % 8 == 0 at all call sites)
    int gx = gridDim.x;
    int nwg = gx * gridDim.y;
    int flat = blockIdx.y * gx + blockIdx.x;
    int cpx = nwg >> 3;
    int swz = (flat & 7) * cpx + (flat >> 3);
    int bx = swz % gx, by = swz / gx;
    size_t m0 = (size_t)bx * 256, n0 = (size_t)by * (NWC * 64);
    int NT = K >> 5;

    const u16* srcA[ACH];
    const u16* srcB[BCH];
    int ldsAb[ACH], ldsBb[BCH];
#pragma unroll
    for (int p = 0; p < ACH; p++) {
        int chunk = p * 512 + tid;
        int s = chunk >> 6;
        int b = (chunk & 63) * 8;
        int bu = b ^ (((b >> 8) & 1) << 4);        // inverse st_16x32 (involution)
        int r = bu >> 5, c = bu & 31;
        srcA[p] = A + (m0 + s * 16 + r) * (size_t)K + c;
        ldsAb[p] = (p * 512 + w * 64) * 8;
    }
#pragma unroll
    for (int p = 0; p < BCH; p++) {
        int chunk = p * 512 + tid;
        int s = chunk >> 6;
        int b = (chunk & 63) * 8;
        int bu = b ^ (((b >> 8) & 1) << 4);
        int r = bu >> 5, c = bu & 31;
        srcB[p] = BT + (n0 + s * 16 + r) * (size_t)K + c;
        ldsBb[p] = 8192 + (p * 512 + w * 64) * 8;
    }

    const int swb = (l15 * 32 + quad * 8) ^ ((l15 >> 3) << 4);

    floatx4 acc[MFR][4];
    const floatx4 fzero = {0.f, 0.f, 0.f, 0.f};
#pragma unroll
    for (int i = 0; i < MFR; i++)
#pragma unroll
        for (int j = 0; j < 4; j++) acc[i][j] = fzero;

    bf16x8 aA0[MFR], bB0[4], aA1[MFR], bB1[4];

    auto STAGE = [&](int j) {
        int rs = j & 3;
        size_t ko = (size_t)j * 32;
        u16* ring = &RING[rs][0];
#pragma unroll
        for (int p = 0; p < ACH; p++) gload16(srcA[p] + ko, ring + ldsAb[p]);
#pragma unroll
        for (int p = 0; p < BCH; p++) gload16(srcB[p] + ko, ring + ldsBb[p]);
    };
    auto READ0 = [&](int rs) {
        const u16* ring = &RING[rs][0];
#pragma unroll
        for (int i2 = 0; i2 < MFR; i2++)
            aA0[i2] = *(const bf16x8*)&ring[(wr * MFR + i2) * 512 + swb];
#pragma unroll
        for (int j2 = 0; j2 < 4; j2++)
            bB0[j2] = *(const bf16x8*)&ring[8192 + (wc * 4 + j2) * 512 + swb];
    };
    auto READ1 = [&](int rs) {
        const u16* ring = &RING[rs][0];
#pragma unroll
        for (int i2 = 0; i2 < MFR; i2++)
            aA1[i2] = *(const bf16x8*)&ring[(wr * MFR + i2) * 512 + swb];
#pragma unroll
        for (int j2 = 0; j2 < 4; j2++)
            bB1[j2] = *(const bf16x8*)&ring[8192 + (wc * 4 + j2) * 512 + swb];
    };
    auto MMA0 = [&]() {
#pragma unroll
        for (int i2 = 0; i2 < MFR; i2++)
#pragma unroll
            for (int j2 = 0; j2 < 4; j2++)
                acc[i2][j2] = __builtin_amdgcn_mfma_f32_16x16x32_bf16(
                    aA0[i2], bB0[j2], acc[i2][j2], 0, 0, 0);
    };
    auto MMA1 = [&]() {
#pragma unroll
        for (int i2 = 0; i2 < MFR; i2++)
#pragma unroll
            for (int j2 = 0; j2 < 4; j2++)
                acc[i2][j2] = __builtin_amdgcn_mfma_f32_16x16x32_bf16(
                    aA1[i2], bB1[j2], acc[i2][j2], 0, 0, 0);
    };

    STAGE(0); STAGE(1); STAGE(2);
    wait_vm6();
    __builtin_amdgcn_s_barrier();
    __builtin_amdgcn_sched_barrier(0);
    READ0(0);

    for (int j = 0; j + 1 < NT; j += 2) {
        if (j + 2 < NT) wait_vm3(); else wait_vm0();
        __builtin_amdgcn_s_barrier();
        __builtin_amdgcn_sched_barrier(0);
        READ1((j + 1) & 3);
        if (j + 3 < NT) STAGE(j + 3);
        MMA0();
        if (j + 2 < NT) {
            if (j + 3 < NT) wait_vm3(); else wait_vm0();
            __builtin_amdgcn_s_barrier();
            __builtin_amdgcn_sched_barrier(0);
            READ0((j + 2) & 3);
            if (j + 4 < NT) STAGE(j + 4);
        }
        MMA1();
    }

#pragma unroll
    for (int i = 0; i < MFR; i++)
#pragma unroll
        for (int j2 = 0; j2 < 4; j2++) {
            size_t col = n0 + wc * 64 + j2 * 16 + l15;
#pragma unroll
            for (int r = 0; r < 4; r++) {
                size_t row = m0 + (size_t)wr * (MFR * 16) + i * 16 + quad * 4 + r;
                if constexpr (MODE == 0) {
                    ((u16*)C0)[row * ldc + col] = f2bf(acc[i][j2][r]);
                } else if constexpr (MODE == 1) {
                    ((float*)C0)[row * ldc + col] = acc[i][j2][r];
                } else if constexpr (MODE == 2) {
                    if (col < 3072)
                        ((u16*)C0)[row * 3072 + col] = f2bf(acc[i][j2][r]);
                    else if (col < 3648)
                        ((u16*)C1)[row * 576 + (col - 3072)] = f2bf(acc[i][j2][r]);
                }
            }
            if constexpr (MODE == 3) {
                int cm = (int)(col & 255);
                size_t row0 = m0 + (size_t)wr * (MFR * 16) + i * 16 + quad * 4;
                if (cm < 128) {
                    // k_nope -> kv PACKED: [row][h*128 + d], ldc 2048
                    size_t cc = (col >> 8) * 128 + cm;
#pragma unroll
                    for (int r = 0; r < 4; r++)
                        ((u16*)C0)[(row0 + r) * 2048 + cc] = f2bf(acc[i][j2][r]);
                } else {
                    // v part -> vt transposed: vt[((b*16+h)*128+vd)*2048 + s], 4 s packed
                    int h = (int)(col >> 8), vd = cm - 128;
                    size_t b = row0 >> 11, s = row0 & 2047;
                    unsigned lo = (unsigned)f2bf(acc[i][j2][0]) | ((unsigned)f2bf(acc[i][j2][1]) << 16);
                    unsigned hi = (unsigned)f2bf(acc[i][j2][2]) | ((unsigned)f2bf(acc[i][j2][3]) << 16);
                    uint2 pk = {lo, hi};
                    *(uint2*)&((u16*)C1)[(((b << 4) + h) * 128 + vd) * 2048 + s] = pk;
                }
            }
        }
}

// ---------------- R9 merged RMSNorm + RoPE (independent data, one dispatch) ----------------
// blocks [0,1024): rmsnorm, wave-per-row (4 rows/block) over kva cols 0..511 -> ckv.
// blocks [1024,3072): rope in-place on qbuf rope-cols + kva cols 512..575 (2 rows/block).
__global__ __launch_bounds__(256) void k_normrope(const u16* __restrict__ kva_c,
                                                  const float* __restrict__ scl,
                                                  u16* __restrict__ ckv,
                                                  u16* __restrict__ qbuf,
                                                  u16* __restrict__ kva) {
    __shared__ float cs_s[2][32], sn_s[2][32];
    int bid = blockIdx.x, tid = threadIdx.x;
    if (bid < 1024) {
        int r = bid * 4 + (tid >> 6), lane = tid & 63;
        const u16* row = kva_c + (size_t)r * 576 + lane * 8;
        uint4 raw = *(const uint4*)row;
        unsigned w[4] = {raw.x, raw.y, raw.z, raw.w};
        float f[8];
        float ss = 0.f;
        for (int t = 0; t < 4; t++) {
            f[2 * t]     = bf2f((u16)(w[t] & 0xffffu));
            f[2 * t + 1] = bf2f((u16)(w[t] >> 16));
            ss += f[2 * t] * f[2 * t] + f[2 * t + 1] * f[2 * t + 1];
        }
        for (int off = 1; off < 64; off <<= 1) ss += __shfl_xor(ss, off, 64);
        float rs = rsqrtf(ss * (1.f / 512.f) + 1e-6f);
        unsigned o[4];
        for (int t = 0; t < 4; t++) {
            u16 lo = f2bf(f[2 * t] * rs * scl[lane * 8 + 2 * t]);
            u16 hi = f2bf(f[2 * t + 1] * rs * scl[lane * 8 + 2 * t + 1]);
            o[t] = (unsigned)lo | ((unsigned)hi << 16);
        }
        uint4 packed = {o[0], o[1], o[2], o[3]};
        *(uint4*)(ckv + (size_t)r * 512 + lane * 8) = packed;
        return;
    }
    int rb2 = bid - 1024;
    int rloc = tid >> 7;
    int task = tid & 127;
    int r = rb2 * 2 + rloc;
    if (tid < 64) {
        int rr = tid >> 5, i = tid & 31;
        int ss = (rb2 * 2 + rr) & 2047;
        float freq = __expf(-0.28782313662425575f * (float)i);  // 10000^(-i/32)
        float ang = (float)ss * freq;
        float sn, cs;
        sincosf(ang, &sn, &cs);
        cs_s[rr][i] = cs; sn_s[rr][i] = sn;
    }
    __syncthreads();
    if (task < 68) {
        int rb = task >> 2, q = task & 3;
        u16* base = (rb < 16) ? qbuf + (size_t)r * 3072 + rb * 192 + 128
                              : kva + (size_t)r * 576 + 512;
        u16* p1 = base + q * 8;
        uint4 x1v = *(uint4*)p1;
        uint4 x2v = *(uint4*)(p1 + 32);
        unsigned w1[4] = {x1v.x, x1v.y, x1v.z, x1v.w};
        unsigned w2[4] = {x2v.x, x2v.y, x2v.z, x2v.w};
        unsigned o1[4], o2[4];
        for (int t2 = 0; t2 < 4; t2++) {
            float a1 = bf2f((u16)(w1[t2] & 0xffffu)), b1 = bf2f((u16)(w1[t2] >> 16));
            float a2 = bf2f((u16)(w2[t2] & 0xffffu)), b2 = bf2f((u16)(w2[t2] >> 16));
            int i0 = q * 8 + t2 * 2, i1 = i0 + 1;
            float c0 = cs_s[rloc][i0], s0 = sn_s[rloc][i0];
            float c1 = cs_s[rloc][i1], s1 = sn_s[rloc][i1];
            o1[t2] = (unsigned)f2bf(a1 * c0 - a2 * s0) | ((unsigned)f2bf(b1 * c1 - b2 * s1) << 16);
            o2[t2] = (unsigned)f2bf(a2 * c0 + a1 * s0) | ((unsigned)f2bf(b2 * c1 + b1 * s1) << 16);
        }
        uint4 y1 = {o1[0], o1[1], o1[2], o1[3]};
        uint4 y2 = {o2[0], o2[1], o2[2], o2[3]};
        *(uint4*)p1 = y1;
        *(uint4*)(p1 + 32) = y2;
    }
}

// ---------------- Flash attention (R3 structure — best measured; kv PACKED ldc 2048) ----------------
// Double-buffered LDS K/V with ODD 16B-slot strides (Kn 136 = 17 slots, Kp 72 = 9 —
// inherently bank-conflict-free), no setprio (hurts this lockstep structure, m190 regime).
__global__ __launch_bounds__(256, 3) void k_attn(const u16* __restrict__ qbuf,
                                                 const u16* __restrict__ kv,
                                                 const u16* __restrict__ kva,
                                                 const u16* __restrict__ vt,
                                                 u16* __restrict__ attno) {
    int tid = threadIdx.x;
    int wave = tid >> 6, lane = tid & 63;
    int quad = lane >> 4, l15 = lane & 15;
    int hb = blockIdx.x;                 // 0..31
    int h = hb & 15, b = hb >> 4;
    int qb = 31 - (int)blockIdx.y;       // descending: longest blocks first
    int qg0 = qb * 64 + wave * 16;       // wave's first q-row
    int row = qg0 + l15;                 // this lane's q-row (S^T col)

    __shared__ __align__(16) u16 Kn[2][32 * 136];
    __shared__ __align__(16) u16 Kp[2][32 * 72];
    __shared__ __align__(16) u16 Vs[2][128 * 40];
    __shared__ __align__(16) u16 P[4][16 * 40];

    const u16* qrp = qbuf + ((size_t)(b * 2048) + qg0 + l15) * 3072 + h * 192;
    bf16x8 qf[6];
    for (int c = 0; c < 6; c++) qf[c] = *(const bf16x8*)&qrp[c * 32 + quad * 8];

    const floatx4 fzero = {0.f, 0.f, 0.f, 0.f};
    floatx4 o[8];
    for (int f = 0; f < 8; f++) o[f] = fzero;
    float lp = 0.f;

    const u16* kvb = kv  + (size_t)(b * 2048) * 2048 + h * 128;   // + key*2048 (packed k_nope)
    const u16* kpb = kva + (size_t)(b * 2048) * 576 + 512;        // + key*576  (roped k_pe)
    const u16* vtb = vt  + (size_t)(b * 16 + h) * 128 * 2048;     // + vd*2048 + key
    const float scale = 0.07216878364870323f;                     // 192^-0.5

    int nkt = qb * 2 + 2;                // ceil((qb*64+63+1)/32)

    // staging chunk maps (16B chunks)
    int kKey0 = tid >> 4,          kOff0 = (tid & 15) * 8;        // Kn: 16 chunks/row
    int kKey1 = (tid + 256) >> 4,  kOff1 = (tid & 15) * 8;
    int pKey  = tid >> 3,          pOff  = (tid & 7) * 8;         // Kp: 8 chunks/row
    int vRow0 = tid >> 2,          vOff0 = (tid & 3) * 8;         // Vs: 4 chunks/row (rows 0..63)
    int vRow1 = (tid + 256) >> 2,  vOff1 = (tid & 3) * 8;         //     rows 64..127

    // prologue: stage tile 0 into buffer 0
    {
        uint4 a = *(const uint4*)&kvb[(size_t)kKey0 * 2048 + kOff0];
        uint4 c = *(const uint4*)&kvb[(size_t)kKey1 * 2048 + kOff1];
        uint4 d = *(const uint4*)&kpb[(size_t)pKey * 576 + pOff];
        uint4 e = *(const uint4*)&vtb[(size_t)vRow0 * 2048 + vOff0];
        uint4 g = *(const uint4*)&vtb[(size_t)vRow1 * 2048 + vOff1];
        *(uint4*)&Kn[0][kKey0 * 136 + kOff0] = a;
        *(uint4*)&Kn[0][kKey1 * 136 + kOff1] = c;
        *(uint4*)&Kp[0][pKey * 72 + pOff] = d;
        *(uint4*)&Vs[0][vRow0 * 40 + vOff0] = e;
        *(uint4*)&Vs[0][vRow1 * 40 + vOff1] = g;
    }
    __syncthreads();

    for (int kt = 0; kt < nkt; kt++) {
        int cur = kt & 1;
        bool have = (kt + 1) < nkt;
        uint4 sA = {}, sB = {}, sC = {}, sD = {}, sE = {};
        if (have) {
            int kb = (kt + 1) * 32;
            sA = *(const uint4*)&kvb[(size_t)(kb + kKey0) * 2048 + kOff0];
            sB = *(const uint4*)&kvb[(size_t)(kb + kKey1) * 2048 + kOff1];
            sC = *(const uint4*)&kpb[(size_t)(kb + pKey) * 576 + pOff];
            sD = *(const uint4*)&vtb[(size_t)vRow0 * 2048 + kb + vOff0];
            sE = *(const uint4*)&vtb[(size_t)vRow1 * 2048 + kb + vOff1];
        }
        if (kt * 32 <= qg0 + 15) {       // tile intersects this wave's causal range
            bf16x8 vf[8];
            for (int f = 0; f < 8; f++)
                vf[f] = *(const bf16x8*)&Vs[cur][(f * 16 + l15) * 40 + quad * 8];
            floatx4 sc[2] = {fzero, fzero};
            for (int hf = 0; hf < 2; hf++) {
                const u16* kn = &Kn[cur][(hf * 16 + l15) * 136];
                const u16* kp = &Kp[cur][(hf * 16 + l15) * 72];
                for (int c = 0; c < 4; c++) {
                    bf16x8 kf = *(const bf16x8*)&kn[c * 32 + quad * 8];
                    sc[hf] = __builtin_amdgcn_mfma_f32_16x16x32_bf16(kf, qf[c], sc[hf], 0, 0, 0);
                }
                for (int c = 0; c < 2; c++) {
                    bf16x8 kf = *(const bf16x8*)&kp[c * 32 + quad * 8];
                    sc[hf] = __builtin_amdgcn_mfma_f32_16x16x32_bf16(kf, qf[4 + c], sc[hf], 0, 0, 0);
                }
            }
            asm volatile("" ::: "memory");
            for (int hf = 0; hf < 2; hf++) {
                int keyb = kt * 32 + hf * 16 + quad * 4;
                float p[4];
                for (int r = 0; r < 4; r++)
                    p[r] = (keyb + r <= row) ? __expf(sc[hf][r] * scale) : 0.f;
                lp += (p[0] + p[1]) + (p[2] + p[3]);
                unsigned d0 = (unsigned)f2bf(p[0]) | ((unsigned)f2bf(p[1]) << 16);
                unsigned d1 = (unsigned)f2bf(p[2]) | ((unsigned)f2bf(p[3]) << 16);
                uint2 pk = {d0, d1};
                *(uint2*)&P[wave][l15 * 40 + hf * 16 + quad * 4] = pk;
            }
            asm volatile("" ::: "memory");
            bf16x8 pa = *(const bf16x8*)&P[wave][l15 * 40 + quad * 8];
            asm volatile("" ::: "memory");
            for (int f = 0; f < 8; f++)
                o[f] = __builtin_amdgcn_mfma_f32_16x16x32_bf16(pa, vf[f], o[f], 0, 0, 0);
        }
        if (have) {
            int nb = cur ^ 1;
            *(uint4*)&Kn[nb][kKey0 * 136 + kOff0] = sA;
            *(uint4*)&Kn[nb][kKey1 * 136 + kOff1] = sB;
            *(uint4*)&Kp[nb][pKey * 72 + pOff] = sC;
            *(uint4*)&Vs[nb][vRow0 * 40 + vOff0] = sD;
            *(uint4*)&Vs[nb][vRow1 * 40 + vOff1] = sE;
        }
        __syncthreads();
    }

    // reduce l across quads (lanes sharing l15 hold partials over key-quads)
    lp += __shfl_xor(lp, 16, 64);
    lp += __shfl_xor(lp, 32, 64);
    float lrow[4];
    for (int r = 0; r < 4; r++) lrow[r] = __shfl(lp, quad * 4 + r, 64);
    for (int f = 0; f < 8; f++)
        for (int r = 0; r < 4; r++) {
            int orow = qg0 + quad * 4 + r;
            float val = o[f][r] / lrow[r];
            attno[((size_t)(b * 2048) + orow) * 2048 + h * 128 + f * 16 + l15] = f2bf(val);
        }
}

extern "C" void kernel_launch(void* const* d_in, const int* in_sizes, int n_in,
                              void* d_out, int out_size, void* d_ws, size_t ws_size,
                              hipStream_t stream) {
    const float* x_raw    = (const float*)d_in[0];
    const float* wq_raw   = (const float*)d_in[1];
    const float* wkva_raw = (const float*)d_in[2];
    const float* wkvb_raw = (const float*)d_in[3];
    const float* wo_raw   = (const float*)d_in[4];
    const float* kvs_raw  = (const float*)d_in[5];
    float* out = (float*)d_out;
    u16* ws = (u16*)d_ws;

    // ---- ws regions (u16 offsets) ----
    // O_ATT  0..8.39M : g12bt (7.60M) -> ckv (2.10M) -> attno (8.39M)
    // O_VT   8.39M    : x_bf (8.39M) -> vt (8.39M, GEMM3 epilogue)
    // O_QB   16.78M   : qbuf (12.58M)
    // O_KVA  29.36M   : kva (2.36M)
    // O_KV   31.72M   : kv2 packed 4096x2048 (8.39M) | wo_t (4.19M) | wkvb_t (2.10M)
    const size_t O_ATT = 0;
    const size_t O_VT  = 8388608;
    const size_t O_QB  = 16777216;
    const size_t O_KVA = 29360128;
    const size_t O_KV  = 31719424;
    const size_t O_WOT = O_KV + 8388608;     // 40108032
    const size_t O_WBT = O_WOT + 4194304;    // 44302336 (+2097152 = 46399488 < 48496640)
    const size_t TOTAL_BYTES = 48496640ull * 2;
    if (ws_size < TOTAL_BYTES) return;   // diagnostic: zeros -> absmax 4.03125

    u16* g12bt  = ws + O_ATT;
    u16* ckv    = ws + O_ATT;            // after GEMM12
    u16* attno  = ws + O_ATT;            // after GEMM3
    u16* x_bf   = ws + O_VT;
    u16* vt     = ws + O_VT;             // written by GEMM3 epilogue
    u16* qbuf   = ws + O_QB;
    u16* kva    = ws + O_KVA;
    u16* kv     = ws + O_KV;             // packed k_nope, ldc 2048
    u16* wo_t   = ws + O_WOT;
    u16* wkvb_t = ws + O_WBT;

    // 1) all preprocessing in one dispatch (x-cast + 4 weight transposes)
    k_preproc<<<17664, 256, 0, stream>>>(x_raw, x_bf, wq_raw, wkva_raw, wkvb_raw, wo_raw,
                                         g12bt, wkvb_t, wo_t);

    // 2) GEMM1+2 fused: N=3712 (29x128), split store -> qbuf (cols<3072), kva (cols 3072..3647)
    k_gemm256<2, 2><<<dim3(16, 29), 512, 0, stream>>>(x_bf, g12bt, qbuf, kva, 2048, 0);

    // 3) rmsnorm + rope merged
    k_normrope<<<3072, 256, 0, stream>>>(kva, kvs_raw, ckv, qbuf, kva);

    // 4) GEMM3 fused: k_nope -> kv (packed), v -> vt (transposed)
    k_gemm256<2, 3><<<dim3(16, 32), 512, 0, stream>>>(ckv, wkvb_t, kv, vt, 512, 4096);

    // 5) attention
    k_attn<<<dim3(32, 32), 256, 0, stream>>>(qbuf, kv, kva, vt, attno);

    // 6) GEMM4 -> f32 out
    k_gemm256<2, 1><<<dim3(16, 16), 512, 0, stream>>>(attno, wo_t, out, nullptr, 2048, 2048);
}

// Round 10
// 354.140 us; speedup vs baseline: 1.1019x; 1.1019x over previous
//
#include <hip/hip_runtime.h>
#include <stdint.h>
#include <stddef.h>

typedef __bf16 bf16x8 __attribute__((ext_vector_type(8)));
typedef float floatx4 __attribute__((ext_vector_type(4)));
typedef unsigned short u16;

__device__ __forceinline__ float bf2f(u16 h) {
    unsigned u = ((unsigned)h) << 16;
    return __builtin_bit_cast(float, u);
}
__device__ __forceinline__ u16 f2bf(float f) {
    unsigned u = __builtin_bit_cast(unsigned, f);
    u += 0x7fffu + ((u >> 16) & 1u);   // round-to-nearest-even
    return (u16)(u >> 16);
}

// async global->LDS, 16B per lane; lds dest is wave-uniform base (+lane*16 implicit)
__device__ __forceinline__ void gload16(const void* g, void* l) {
    __builtin_amdgcn_global_load_lds(
        (const __attribute__((address_space(1))) uint32_t*)g,
        (__attribute__((address_space(3))) uint32_t*)l, 16, 0, 0);
}

// counted vmcnt waits (literal strings required)
__device__ __forceinline__ void wait_vm8() { asm volatile("s_waitcnt vmcnt(8)" ::: "memory"); }
__device__ __forceinline__ void wait_vm6() { asm volatile("s_waitcnt vmcnt(6)" ::: "memory"); }
__device__ __forceinline__ void wait_vm4() { asm volatile("s_waitcnt vmcnt(4)" ::: "memory"); }
__device__ __forceinline__ void wait_vm3() { asm volatile("s_waitcnt vmcnt(3)" ::: "memory"); }
__device__ __forceinline__ void wait_vm0() { asm volatile("s_waitcnt vmcnt(0)" ::: "memory"); }

// ---------------- x: f32 -> bf16, vectorized (8/thread) ----------------
__global__ __launch_bounds__(256) void k_conv_x(const float* __restrict__ in,
                                                u16* __restrict__ out, int n8) {
    int i = blockIdx.x * 256 + threadIdx.x;
    if (i >= n8) return;
    const float* f = in + (size_t)i * 8;
    unsigned o[4];
    for (int t = 0; t < 4; t++) {
        u16 lo = f2bf(f[2 * t]), hi = f2bf(f[2 * t + 1]);
        o[t] = (unsigned)lo | ((unsigned)hi << 16);
    }
    uint4 p = {o[0], o[1], o[2], o[3]};
    *(uint4*)&out[(size_t)i * 8] = p;
}

// ---------------- weight: f32 (K,N) -> bf16 transposed (Npad,K), zero pad ----------------
__global__ __launch_bounds__(256) void k_convT(const float* __restrict__ in,
                                               u16* __restrict__ out, int K, int N) {
    __shared__ u16 t[32][33];
    int k0 = blockIdx.x * 32, n0 = blockIdx.y * 32;
    int c = threadIdx.x & 31, r8 = threadIdx.x >> 5;
    for (int j = 0; j < 4; j++) {
        int row = r8 + j * 8;
        int n = n0 + c;
        t[row][c] = (n < N) ? f2bf(in[(size_t)(k0 + row) * N + n]) : (u16)0;
    }
    __syncthreads();
    for (int j = 0; j < 4; j++) {
        int row = r8 + j * 8;
        out[(size_t)(n0 + row) * K + k0 + c] = t[c][row];
    }
}

// ---------------- 256xBN ring-pipelined GEMM (R10) ----------------
// BM=256, BN=NWC*64. 512 thr = 8 waves; wave (wr,wc) owns (MFR*16) x 64 output.
// 4-slot LDS ring of BK=32 subtiles, prefetch 3 ahead, counted vmcnt (never 0 in
// steady loop), one barrier per subtile.
// NWC=2 (96KB ring): fragments double-buffered in NAMED register sets (R8-proven).
// NWC=4 (128KB ring, 128x64/wave = HALF the LDS bytes per MFMA of NWC=2):
//   single-buffered fragments — full dbuf at MFR=8 would spill (~290 VGPR);
//   aA1/bB1 are DCE'd in this instantiation.
// st_16x32 swizzle in 1KiB subtiles; gload_lds writes linear, global source
// inverse-swizzled (rule #21). Requires M%256==0, N%BN==0, K%64==0, K/32>=4.
// MODE: 0 = u16 out; 1 = f32 out;
//       2 = split store: col<3072 -> C0 u16 ldc 3072; 3072<=col<3648 -> C1 u16 ldc 576;
//           cols >=3648 discarded (pad).
//       3 = GEMM3 fusion: (col%256)<128 -> kv (C0, ldc 4096, u16);
//           else v-part -> vt (C1) TRANSPOSED: vt[((b*16+h)*128+vd)*2048 + s], uint2 packed.
template <int NWC, int MODE>
__global__ __launch_bounds__(512, 2) void k_gemm256(const u16* __restrict__ A,
                                                    const u16* __restrict__ BT,
                                                    void* __restrict__ C0,
                                                    void* __restrict__ C1,
                                                    int K, int ldc) {
    constexpr int MFR = 16 / (8 / NWC);     // NWC=2 -> 4, NWC=4 -> 8
    constexpr int ACH = 2;
    constexpr int BCH = NWC / 2;
    constexpr int SLOT = 8192 + NWC * 2048;
    __shared__ __align__(16) u16 RING[4][SLOT];
    int tid = threadIdx.x;
    int w = tid >> 6, lane = tid & 63;
    int l15 = lane & 15, quad = lane >> 4;
    int wr = w / NWC, wc = w % NWC;

    // XCD-aware swizzle (bijective: nwg % 8 == 0 at all call sites)
    int gx = gridDim.x;
    int nwg = gx * gridDim.y;
    int flat = blockIdx.y * gx + blockIdx.x;
    int cpx = nwg >> 3;
    int swz = (flat & 7) * cpx + (flat >> 3);
    int bx = swz % gx, by = swz / gx;
    size_t m0 = (size_t)bx * 256, n0 = (size_t)by * (NWC * 64);
    int NT = K >> 5;

    const u16* srcA[ACH];
    const u16* srcB[BCH];
    int ldsAb[ACH], ldsBb[BCH];
#pragma unroll
    for (int p = 0; p < ACH; p++) {
        int chunk = p * 512 + tid;
        int s = chunk >> 6;
        int b = (chunk & 63) * 8;
        int bu = b ^ (((b >> 8) & 1) << 4);        // inverse st_16x32 (involution)
        int r = bu >> 5, c = bu & 31;
        srcA[p] = A + (m0 + s * 16 + r) * (size_t)K + c;
        ldsAb[p] = (p * 512 + w * 64) * 8;
    }
#pragma unroll
    for (int p = 0; p < BCH; p++) {
        int chunk = p * 512 + tid;
        int s = chunk >> 6;
        int b = (chunk & 63) * 8;
        int bu = b ^ (((b >> 8) & 1) << 4);
        int r = bu >> 5, c = bu & 31;
        srcB[p] = BT + (n0 + s * 16 + r) * (size_t)K + c;
        ldsBb[p] = 8192 + (p * 512 + w * 64) * 8;
    }

    const int swb = (l15 * 32 + quad * 8) ^ ((l15 >> 3) << 4);

    floatx4 acc[MFR][4];
    const floatx4 fzero = {0.f, 0.f, 0.f, 0.f};
#pragma unroll
    for (int i = 0; i < MFR; i++)
#pragma unroll
        for (int j = 0; j < 4; j++) acc[i][j] = fzero;

    bf16x8 aA0[MFR], bB0[4], aA1[MFR], bB1[4];

    auto STAGE = [&](int j) {
        int rs = j & 3;
        size_t ko = (size_t)j * 32;
        u16* ring = &RING[rs][0];
#pragma unroll
        for (int p = 0; p < ACH; p++) gload16(srcA[p] + ko, ring + ldsAb[p]);
#pragma unroll
        for (int p = 0; p < BCH; p++) gload16(srcB[p] + ko, ring + ldsBb[p]);
    };
    auto READ0 = [&](int rs) {
        const u16* ring = &RING[rs][0];
#pragma unroll
        for (int i2 = 0; i2 < MFR; i2++)
            aA0[i2] = *(const bf16x8*)&ring[(wr * MFR + i2) * 512 + swb];
#pragma unroll
        for (int j2 = 0; j2 < 4; j2++)
            bB0[j2] = *(const bf16x8*)&ring[8192 + (wc * 4 + j2) * 512 + swb];
    };
    auto READ1 = [&](int rs) {
        const u16* ring = &RING[rs][0];
#pragma unroll
        for (int i2 = 0; i2 < MFR; i2++)
            aA1[i2] = *(const bf16x8*)&ring[(wr * MFR + i2) * 512 + swb];
#pragma unroll
        for (int j2 = 0; j2 < 4; j2++)
            bB1[j2] = *(const bf16x8*)&ring[8192 + (wc * 4 + j2) * 512 + swb];
    };
    auto MMA0 = [&]() {
#pragma unroll
        for (int i2 = 0; i2 < MFR; i2++)
#pragma unroll
            for (int j2 = 0; j2 < 4; j2++)
                acc[i2][j2] = __builtin_amdgcn_mfma_f32_16x16x32_bf16(
                    aA0[i2], bB0[j2], acc[i2][j2], 0, 0, 0);
    };
    auto MMA1 = [&]() {
#pragma unroll
        for (int i2 = 0; i2 < MFR; i2++)
#pragma unroll
            for (int j2 = 0; j2 < 4; j2++)
                acc[i2][j2] = __builtin_amdgcn_mfma_f32_16x16x32_bf16(
                    aA1[i2], bB1[j2], acc[i2][j2], 0, 0, 0);
    };

    STAGE(0); STAGE(1); STAGE(2);

    if constexpr (NWC == 4) {
        // single-buffered fragment path (CH=4: prologue wait 8, steady wait 8, tail 8/4/0)
        int j = 0;
        for (; j + 3 < NT; j++) {
            wait_vm8();
            __builtin_amdgcn_s_barrier();
            __builtin_amdgcn_sched_barrier(0);
            READ0(j & 3);
            STAGE(j + 3);
            __builtin_amdgcn_sched_barrier(0);
            MMA0();
        }
        {
            wait_vm8();
            __builtin_amdgcn_s_barrier();
            __builtin_amdgcn_sched_barrier(0);
            READ0(j & 3); MMA0(); j++;
        }
        {
            wait_vm4();
            __builtin_amdgcn_s_barrier();
            __builtin_amdgcn_sched_barrier(0);
            READ0(j & 3); MMA0(); j++;
        }
        {
            wait_vm0();
            __builtin_amdgcn_s_barrier();
            __builtin_amdgcn_sched_barrier(0);
            READ0(j & 3); MMA0();
        }
    } else {
        // fragment double-buffer path (R8-proven; CH=3)
        wait_vm6();
        __builtin_amdgcn_s_barrier();
        __builtin_amdgcn_sched_barrier(0);
        READ0(0);
        for (int j = 0; j + 1 < NT; j += 2) {
            if (j + 2 < NT) wait_vm3(); else wait_vm0();
            __builtin_amdgcn_s_barrier();
            __builtin_amdgcn_sched_barrier(0);
            READ1((j + 1) & 3);
            if (j + 3 < NT) STAGE(j + 3);
            MMA0();
            if (j + 2 < NT) {
                if (j + 3 < NT) wait_vm3(); else wait_vm0();
                __builtin_amdgcn_s_barrier();
                __builtin_amdgcn_sched_barrier(0);
                READ0((j + 2) & 3);
                if (j + 4 < NT) STAGE(j + 4);
            }
            MMA1();
        }
    }

#pragma unroll
    for (int i = 0; i < MFR; i++)
#pragma unroll
        for (int j2 = 0; j2 < 4; j2++) {
            size_t col = n0 + wc * 64 + j2 * 16 + l15;
#pragma unroll
            for (int r = 0; r < 4; r++) {
                size_t row = m0 + (size_t)wr * (MFR * 16) + i * 16 + quad * 4 + r;
                if constexpr (MODE == 0) {
                    ((u16*)C0)[row * ldc + col] = f2bf(acc[i][j2][r]);
                } else if constexpr (MODE == 1) {
                    ((float*)C0)[row * ldc + col] = acc[i][j2][r];
                } else if constexpr (MODE == 2) {
                    if (col < 3072)
                        ((u16*)C0)[row * 3072 + col] = f2bf(acc[i][j2][r]);
                    else if (col < 3648)
                        ((u16*)C1)[row * 576 + (col - 3072)] = f2bf(acc[i][j2][r]);
                }
            }
            if constexpr (MODE == 3) {
                int cm = (int)(col & 255);
                size_t row0 = m0 + (size_t)wr * (MFR * 16) + i * 16 + quad * 4;
                if (cm < 128) {
                    // k_nope part -> kv (v-half of kv left unwritten; never read)
#pragma unroll
                    for (int r = 0; r < 4; r++)
                        ((u16*)C0)[(row0 + r) * 4096 + col] = f2bf(acc[i][j2][r]);
                } else {
                    // v part -> vt transposed: vt[((b*16+h)*128+vd)*2048 + s], 4 s packed
                    int h = (int)(col >> 8), vd = cm - 128;
                    size_t b = row0 >> 11, s = row0 & 2047;
                    unsigned lo = (unsigned)f2bf(acc[i][j2][0]) | ((unsigned)f2bf(acc[i][j2][1]) << 16);
                    unsigned hi = (unsigned)f2bf(acc[i][j2][2]) | ((unsigned)f2bf(acc[i][j2][3]) << 16);
                    uint2 pk = {lo, hi};
                    *(uint2*)&((u16*)C1)[(((b << 4) + h) * 128 + vd) * 2048 + s] = pk;
                }
            }
        }
}

// ---------------- RMSNorm over first 512 cols of kva rows -> ckv ----------------
__global__ __launch_bounds__(64) void k_rmsnorm(const u16* __restrict__ kva,
                                                const float* __restrict__ scl,
                                                u16* __restrict__ ckv) {
    int r = blockIdx.x, lane = threadIdx.x;
    const u16* row = kva + (size_t)r * 576 + lane * 8;
    uint4 raw = *(const uint4*)row;
    unsigned w[4] = {raw.x, raw.y, raw.z, raw.w};
    float f[8];
    float ss = 0.f;
    for (int t = 0; t < 4; t++) {
        f[2 * t]     = bf2f((u16)(w[t] & 0xffffu));
        f[2 * t + 1] = bf2f((u16)(w[t] >> 16));
        ss += f[2 * t] * f[2 * t] + f[2 * t + 1] * f[2 * t + 1];
    }
    for (int off = 1; off < 64; off <<= 1) ss += __shfl_xor(ss, off, 64);
    float rs = rsqrtf(ss * (1.f / 512.f) + 1e-6f);
    unsigned o[4];
    for (int t = 0; t < 4; t++) {
        u16 lo = f2bf(f[2 * t] * rs * scl[lane * 8 + 2 * t]);
        u16 hi = f2bf(f[2 * t + 1] * rs * scl[lane * 8 + 2 * t + 1]);
        o[t] = (unsigned)lo | ((unsigned)hi << 16);
    }
    uint4 packed = {o[0], o[1], o[2], o[3]};
    *(uint4*)(ckv + (size_t)r * 512 + lane * 8) = packed;
}

// ---------------- RoPE in-place (vectorized uint4 pair loads, 2 rows/block) ----------------
__global__ __launch_bounds__(256) void k_rope(u16* __restrict__ qbuf, u16* __restrict__ kva) {
    int tid = threadIdx.x;
    int rloc = tid >> 7;              // 0..1: which of the block's 2 rows
    int task = tid & 127;             // 0..127, active < 68
    int r = blockIdx.x * 2 + rloc;
    __shared__ float cs_s[2][32], sn_s[2][32];
    if (tid < 64) {
        int rr = tid >> 5, i = tid & 31;
        int ss = (blockIdx.x * 2 + rr) & 2047;
        float freq = __expf(-0.28782313662425575f * (float)i);  // 10000^(-i/32)
        float ang = (float)ss * freq;
        float sn, cs;
        sincosf(ang, &sn, &cs);
        cs_s[rr][i] = cs; sn_s[rr][i] = sn;
    }
    __syncthreads();
    if (task < 68) {
        int rb = task >> 2, q = task & 3;   // rope-block (16 q-heads + 1 k), quarter
        u16* base = (rb < 16) ? qbuf + (size_t)r * 3072 + rb * 192 + 128
                              : kva + (size_t)r * 576 + 512;
        u16* p1 = base + q * 8;
        uint4 x1v = *(uint4*)p1;
        uint4 x2v = *(uint4*)(p1 + 32);
        unsigned w1[4] = {x1v.x, x1v.y, x1v.z, x1v.w};
        unsigned w2[4] = {x2v.x, x2v.y, x2v.z, x2v.w};
        unsigned o1[4], o2[4];
        for (int t2 = 0; t2 < 4; t2++) {
            float a1 = bf2f((u16)(w1[t2] & 0xffffu)), b1 = bf2f((u16)(w1[t2] >> 16));
            float a2 = bf2f((u16)(w2[t2] & 0xffffu)), b2 = bf2f((u16)(w2[t2] >> 16));
            int i0 = q * 8 + t2 * 2, i1 = i0 + 1;
            float c0 = cs_s[rloc][i0], s0 = sn_s[rloc][i0];
            float c1 = cs_s[rloc][i1], s1 = sn_s[rloc][i1];
            o1[t2] = (unsigned)f2bf(a1 * c0 - a2 * s0) | ((unsigned)f2bf(b1 * c1 - b2 * s1) << 16);
            o2[t2] = (unsigned)f2bf(a2 * c0 + a1 * s0) | ((unsigned)f2bf(b2 * c1 + b1 * s1) << 16);
        }
        uint4 y1 = {o1[0], o1[1], o1[2], o1[3]};
        uint4 y2 = {o2[0], o2[1], o2[2], o2[3]};
        *(uint4*)p1 = y1;
        *(uint4*)(p1 + 32) = y2;
    }
}

// ---------------- Flash attention (R3 structure — best measured) ----------------
// Double-buffered LDS K/V with ODD 16B-slot strides (Kn 136 = 17 slots, Kp 72 = 9 —
// inherently bank-conflict-free), no setprio (hurts this lockstep structure, m190 regime).
__global__ __launch_bounds__(256, 3) void k_attn(const u16* __restrict__ qbuf,
                                                 const u16* __restrict__ kv,
                                                 const u16* __restrict__ kva,
                                                 const u16* __restrict__ vt,
                                                 u16* __restrict__ attno) {
    int tid = threadIdx.x;
    int wave = tid >> 6, lane = tid & 63;
    int quad = lane >> 4, l15 = lane & 15;
    int hb = blockIdx.x;                 // 0..31
    int h = hb & 15, b = hb >> 4;
    int qb = 31 - (int)blockIdx.y;       // descending: longest blocks first
    int qg0 = qb * 64 + wave * 16;       // wave's first q-row
    int row = qg0 + l15;                 // this lane's q-row (S^T col)

    __shared__ __align__(16) u16 Kn[2][32 * 136];
    __shared__ __align__(16) u16 Kp[2][32 * 72];
    __shared__ __align__(16) u16 Vs[2][128 * 40];
    __shared__ __align__(16) u16 P[4][16 * 40];

    const u16* qrp = qbuf + ((size_t)(b * 2048) + qg0 + l15) * 3072 + h * 192;
    bf16x8 qf[6];
    for (int c = 0; c < 6; c++) qf[c] = *(const bf16x8*)&qrp[c * 32 + quad * 8];

    const floatx4 fzero = {0.f, 0.f, 0.f, 0.f};
    floatx4 o[8];
    for (int f = 0; f < 8; f++) o[f] = fzero;
    float lp = 0.f;

    const u16* kvb = kv  + (size_t)(b * 2048) * 4096 + h * 256;   // + key*4096 (k_nope)
    const u16* kpb = kva + (size_t)(b * 2048) * 576 + 512;        // + key*576  (roped k_pe)
    const u16* vtb = vt  + (size_t)(b * 16 + h) * 128 * 2048;     // + vd*2048 + key
    const float scale = 0.07216878364870323f;                     // 192^-0.5

    int nkt = qb * 2 + 2;                // ceil((qb*64+63+1)/32)

    // staging chunk maps (16B chunks)
    int kKey0 = tid >> 4,          kOff0 = (tid & 15) * 8;        // Kn: 16 chunks/row
    int kKey1 = (tid + 256) >> 4,  kOff1 = (tid & 15) * 8;
    int pKey  = tid >> 3,          pOff  = (tid & 7) * 8;         // Kp: 8 chunks/row
    int vRow0 = tid >> 2,          vOff0 = (tid & 3) * 8;         // Vs: 4 chunks/row (rows 0..63)
    int vRow1 = (tid + 256) >> 2,  vOff1 = (tid & 3) * 8;         //     rows 64..127

    // prologue: stage tile 0 into buffer 0
    {
        uint4 a = *(const uint4*)&kvb[(size_t)kKey0 * 4096 + kOff0];
        uint4 c = *(const uint4*)&kvb[(size_t)kKey1 * 4096 + kOff1];
        uint4 d = *(const uint4*)&kpb[(size_t)pKey * 576 + pOff];
        uint4 e = *(const uint4*)&vtb[(size_t)vRow0 * 2048 + vOff0];
        uint4 g = *(const uint4*)&vtb[(size_t)vRow1 * 2048 + vOff1];
        *(uint4*)&Kn[0][kKey0 * 136 + kOff0] = a;
        *(uint4*)&Kn[0][kKey1 * 136 + kOff1] = c;
        *(uint4*)&Kp[0][pKey * 72 + pOff] = d;
        *(uint4*)&Vs[0][vRow0 * 40 + vOff0] = e;
        *(uint4*)&Vs[0][vRow1 * 40 + vOff1] = g;
    }
    __syncthreads();

    for (int kt = 0; kt < nkt; kt++) {
        int cur = kt & 1;
        bool have = (kt + 1) < nkt;
        uint4 sA = {}, sB = {}, sC = {}, sD = {}, sE = {};
        if (have) {
            int kb = (kt + 1) * 32;
            sA = *(const uint4*)&kvb[(size_t)(kb + kKey0) * 4096 + kOff0];
            sB = *(const uint4*)&kvb[(size_t)(kb + kKey1) * 4096 + kOff1];
            sC = *(const uint4*)&kpb[(size_t)(kb + pKey) * 576 + pOff];
            sD = *(const uint4*)&vtb[(size_t)vRow0 * 2048 + kb + vOff0];
            sE = *(const uint4*)&vtb[(size_t)vRow1 * 2048 + kb + vOff1];
        }
        if (kt * 32 <= qg0 + 15) {       // tile intersects this wave's causal range
            bf16x8 vf[8];
            for (int f = 0; f < 8; f++)
                vf[f] = *(const bf16x8*)&Vs[cur][(f * 16 + l15) * 40 + quad * 8];
            floatx4 sc[2] = {fzero, fzero};
            for (int hf = 0; hf < 2; hf++) {
                const u16* kn = &Kn[cur][(hf * 16 + l15) * 136];
                const u16* kp = &Kp[cur][(hf * 16 + l15) * 72];
                for (int c = 0; c < 4; c++) {
                    bf16x8 kf = *(const bf16x8*)&kn[c * 32 + quad * 8];
                    sc[hf] = __builtin_amdgcn_mfma_f32_16x16x32_bf16(kf, qf[c], sc[hf], 0, 0, 0);
                }
                for (int c = 0; c < 2; c++) {
                    bf16x8 kf = *(const bf16x8*)&kp[c * 32 + quad * 8];
                    sc[hf] = __builtin_amdgcn_mfma_f32_16x16x32_bf16(kf, qf[4 + c], sc[hf], 0, 0, 0);
                }
            }
            asm volatile("" ::: "memory");
            for (int hf = 0; hf < 2; hf++) {
                int keyb = kt * 32 + hf * 16 + quad * 4;
                float p[4];
                for (int r = 0; r < 4; r++)
                    p[r] = (keyb + r <= row) ? __expf(sc[hf][r] * scale) : 0.f;
                lp += (p[0] + p[1]) + (p[2] + p[3]);
                unsigned d0 = (unsigned)f2bf(p[0]) | ((unsigned)f2bf(p[1]) << 16);
                unsigned d1 = (unsigned)f2bf(p[2]) | ((unsigned)f2bf(p[3]) << 16);
                uint2 pk = {d0, d1};
                *(uint2*)&P[wave][l15 * 40 + hf * 16 + quad * 4] = pk;
            }
            asm volatile("" ::: "memory");
            bf16x8 pa = *(const bf16x8*)&P[wave][l15 * 40 + quad * 8];
            asm volatile("" ::: "memory");
            for (int f = 0; f < 8; f++)
                o[f] = __builtin_amdgcn_mfma_f32_16x16x32_bf16(pa, vf[f], o[f], 0, 0, 0);
        }
        if (have) {
            int nb = cur ^ 1;
            *(uint4*)&Kn[nb][kKey0 * 136 + kOff0] = sA;
            *(uint4*)&Kn[nb][kKey1 * 136 + kOff1] = sB;
            *(uint4*)&Kp[nb][pKey * 72 + pOff] = sC;
            *(uint4*)&Vs[nb][vRow0 * 40 + vOff0] = sD;
            *(uint4*)&Vs[nb][vRow1 * 40 + vOff1] = sE;
        }
        __syncthreads();
    }

    // reduce l across quads (lanes sharing l15 hold partials over key-quads)
    lp += __shfl_xor(lp, 16, 64);
    lp += __shfl_xor(lp, 32, 64);
    float lrow[4];
    for (int r = 0; r < 4; r++) lrow[r] = __shfl(lp, quad * 4 + r, 64);
    for (int f = 0; f < 8; f++)
        for (int r = 0; r < 4; r++) {
            int orow = qg0 + quad * 4 + r;
            float val = o[f][r] / lrow[r];
            attno[((size_t)(b * 2048) + orow) * 2048 + h * 128 + f * 16 + l15] = f2bf(val);
        }
}

extern "C" void kernel_launch(void* const* d_in, const int* in_sizes, int n_in,
                              void* d_out, int out_size, void* d_ws, size_t ws_size,
                              hipStream_t stream) {
    const float* x_raw    = (const float*)d_in[0];
    const float* wq_raw   = (const float*)d_in[1];
    const float* wkva_raw = (const float*)d_in[2];
    const float* wkvb_raw = (const float*)d_in[3];
    const float* wo_raw   = (const float*)d_in[4];
    const float* kvs_raw  = (const float*)d_in[5];
    float* out = (float*)d_out;
    u16* ws = (u16*)d_ws;

    // ---- ws regions (u16 offsets) — R8 layout; g12bt now padded to 3840 rows ----
    const size_t O_ATT = 0;          // g12bt (3840x2048=7.86M u16) -> {ckv, wkvb_t} -> attno
    const size_t O_VT  = 8388608;    // x_bf -> vt
    const size_t O_QB  = 16777216;   // qbuf -> wo_t
    const size_t O_KVA = 29360128;   // kva
    const size_t O_KV  = 31719424;   // kv (ldc 4096, v-half unwritten)
    const size_t TOTAL_BYTES = 48496640ull * 2;
    if (ws_size < TOTAL_BYTES) return;   // diagnostic: zeros -> absmax 4.03125

    u16* g12bt  = ws + O_ATT;            // merged [wq_t (3072 rows); wkva_t (576+pad to 768 rows)]
    u16* ckv    = ws + O_ATT;            // after GEMM12
    u16* wkvb_t = ws + O_ATT + 2097152;
    u16* attno  = ws + O_ATT;            // after GEMM3
    u16* x_bf   = ws + O_VT;
    u16* vt     = ws + O_VT;             // written by GEMM3 epilogue
    u16* qbuf   = ws + O_QB;
    u16* wo_t   = ws + O_QB;             // after attn
    u16* kva    = ws + O_KVA;
    u16* kv     = ws + O_KV;

    k_conv_x<<<4096, 256, 0, stream>>>(x_raw, x_bf, 1048576);
    // merged BT: rows 0..3071 = wq^T, rows 3072..3839 = wkva^T zero-padded (N=576 -> 768 rows)
    k_convT<<<dim3(64, 96), 256, 0, stream>>>(wq_raw, g12bt, 2048, 3072);
    k_convT<<<dim3(64, 24), 256, 0, stream>>>(wkva_raw, g12bt + (size_t)3072 * 2048, 2048, 576);

    // GEMM1+2 fused, NWC=4 (N padded to 3840 = 15x256): split store -> qbuf / kva, pad discarded
    k_gemm256<4, 2><<<dim3(16, 15), 512, 0, stream>>>(x_bf, g12bt, qbuf, kva, 2048, 0);

    k_rmsnorm<<<4096, 64, 0, stream>>>(kva, kvs_raw, ckv);
    k_convT<<<dim3(16, 128), 256, 0, stream>>>(wkvb_raw, wkvb_t, 512, 4096);
    // GEMM3 fused, NWC=4 (256 blocks = 1/CU, one round): k_nope -> kv, v -> vt (transposed)
    k_gemm256<4, 3><<<dim3(16, 16), 512, 0, stream>>>(ckv, wkvb_t, kv, vt, 512, 4096);

    k_rope<<<2048, 256, 0, stream>>>(qbuf, kva);

    k_attn<<<dim3(32, 32), 256, 0, stream>>>(qbuf, kv, kva, vt, attno);

    k_convT<<<dim3(64, 64), 256, 0, stream>>>(wo_raw, wo_t, 2048, 2048);
    k_gemm256<2, 1><<<dim3(16, 16), 512, 0, stream>>>(attno, wo_t, out, nullptr, 2048, 2048); // GEMM4 -> f32
}